// Round 5
// baseline (313.593 us; speedup 1.0000x reference)
//
#include <hip/hip_runtime.h>

#define RAD 6
#define KS 13
#define DIM 192
#define CH 3
#define W4C 48                 // float4 per row
#define PLANE4 (DIM * W4C)     // f4 per (d) plane = 9216
#define VOL4 (DIM * PLANE4)    // f4 per channel
#define VOL (DIM * DIM * DIM)
#define TOTAL (CH * VOL)       // 21,233,664 floats

// ---------------- fused kernel geometry ----------------
#define HT 8                   // output h-rows per block
#define HL 20                  // staged rows = HT + 2*RAD
#define DT 16                  // output depths per block
#define NDT 12                 // 12*16 = 192 exact
#define NSTEP (DT + 2 * RAD)   // 28 planes streamed per block
#define NTF 192
#define NHT (DIM / HT)         // 24 h-tiles
#define GRIDF (CH * NHT * NDT) // 864 blocks = 8 XCD * 108
#define RS 49                  // raw LDS row stride in f4 (48 + 1 pad)
#define WCS 49                 // w-conv LDS row stride in f4

typedef float nt4 __attribute__((ext_vector_type(4)));  // for nontemporal stores

// Extract 1D gaussian: g3[i][j][k] = g1[i]*g1[j]*g1[k], sum(g1)=1 -> row-sum recovers g1.
__global__ void g1_extract_kernel(const float* __restrict__ w, float* __restrict__ g1) {
    int i = threadIdx.x;
    if (i < KS) {
        float s = 0.f;
        for (int j = 0; j < KS * KS; ++j) s += w[i * KS * KS + j];
        g1[i] = s;
    }
}

// ---------------------------------------------------------------------------
// Single-pass separable conv, latency-hidden: block = (c, 8 h-rows, 16 depths).
// Streams NSTEP=28 planes. Pipeline per step (T14 async-STAGE split):
//   issue: 5 global_load_dwordx4 for plane s+1 -> regs (in flight all step)
//   W:     conv of plane s from raw LDS -> wcb LDS       } barrier A
//   H:     14-tap column read of wcb -> whA/whB (regs)
//   D:     13-deep register window dot; nontemporal store
//   write: prefetch regs -> raw (after A: W-readers done) } barrier B
// Loads span the whole compute phase instead of stalling at the top.
// ---------------------------------------------------------------------------
__global__ __launch_bounds__(NTF) void conv3d_fused(const float* __restrict__ in,
                                                    float* __restrict__ out,
                                                    const float* __restrict__ g1v) {
    __shared__ float4 raw[HL * RS];
    __shared__ float4 wcb[HL * WCS];

    int bid = blockIdx.x;
    // bijective XCD swizzle: 864 = 8 * 108
    bid = (bid & 7) * (GRIDF / 8) + (bid >> 3);
    const int ht = bid % NHT;
    const int dt = (bid / NHT) % NDT;
    const int c  = bid / (NHT * NDT);
    const int h0 = ht * HT;
    const int d0 = dt * DT;
    const int t  = threadIdx.x;

    float g[KS];
#pragma unroll
    for (int k = 0; k < KS; ++k) g[k] = g1v[k];

    const float4* __restrict__ in4 = (const float4*)in;
    float4* __restrict__ out4 = (float4*)out;
    const float4 z4 = make_float4(0.f, 0.f, 0.f, 0.f);

    // ---- roles ----
    const int w4 = t % W4C;          // 0..47
    const int pj = t / W4C;          // 0..3

    // staging: thread stages rows (pj + 4i), col w4  (5 * 192 = 960 = 20*48 exact)
    int srcOff[5];
    int dstOff[5];
#pragma unroll
    for (int i = 0; i < 5; ++i) {
        int r = pj + 4 * i;
        int h = h0 - RAD + r;
        int hc = min(max(h, 0), DIM - 1);
        srcOff[i] = c * VOL4 + hc * W4C + w4;     // + dp*PLANE4 per step
        dstOff[i] = r * RS + w4;
    }

    // W-run role (t < 160): row u = t>>3, segment seg = t&7 (6 f4 outputs each)
    const int u_run = t >> 3;
    const int seg = t & 7;
    const bool runActive = (t < HL * 8);
    const int hrow = h0 - RAD + u_run;
    const float rowScale = (hrow >= 0 && hrow < DIM) ? 1.f : 0.f;  // h zero-pad
    const bool segLo = (seg == 0);
    const bool segHi = (seg == 7);
    const int rawRow = u_run * RS;
    const int wcBase = u_run * WCS + seg * 6;

    // H/D role: column w4, output rows h0+2pj, h0+2pj+1
    const int tapBase = 2 * pj * WCS + w4;
    const int outBase = c * VOL4 + (h0 + 2 * pj) * W4C + w4;  // + o*PLANE4

    float4 WA[14], WB[14];
#pragma unroll
    for (int j = 0; j < 14; ++j) { WA[j] = z4; WB[j] = z4; }

    // ---- prologue: stage plane dp(0) = d0 - RAD (valid for all dt > 0) ----
    {
        const int dp0 = d0 - RAD;
        if (dp0 >= 0) {                       // block-uniform
            const int pb = dp0 * PLANE4;
#pragma unroll
            for (int i = 0; i < 5; ++i) raw[dstOff[i]] = in4[pb + srcOff[i]];
        }
        __syncthreads();
    }

#pragma unroll 1
    for (int s2 = 0; s2 < NSTEP; s2 += 2) {
#pragma unroll
        for (int off = 0; off < 2; ++off) {
            const int s = s2 + off;
            const int dp = d0 - RAD + s;               // plane in raw now
            const bool dpv = (dp >= 0) && (dp < DIM);  // block-uniform
            const int dpn = dp + 1;                    // plane to prefetch
            const bool nv = (s + 1 < NSTEP) && (dpn >= 0) && (dpn < DIM);

            // ---- issue prefetch for next plane (non-blocking) ----
            float4 pf[5];
            if (nv) {
                const int pb = dpn * PLANE4;
#pragma unroll
                for (int i = 0; i < 5; ++i) pf[i] = in4[pb + srcOff[i]];
            }

            float4 whA = z4, whB = z4;
            if (dpv) {
                // ---- W conv: runs of 6 f4 from raw -> wcb ----
                if (runActive) {
                    float F[40];
#pragma unroll
                    for (int i = 0; i < 10; ++i) {
                        int cw = seg * 6 - 2 + i;
                        int cwc = min(max(cw, 0), W4C - 1);
                        float4 v = raw[rawRow + cwc];
                        if ((segLo && i < 2) || (segHi && i >= 8)) v = z4;  // w zero-pad
                        F[4*i+0] = v.x; F[4*i+1] = v.y;
                        F[4*i+2] = v.z; F[4*i+3] = v.w;
                    }
#pragma unroll
                    for (int q = 0; q < 6; ++q) {
                        float ax = 0.f, ay = 0.f, az = 0.f, aw = 0.f;
#pragma unroll
                        for (int k = 0; k < KS; ++k) {
                            const float gw = g[k];
                            ax += gw * F[4*q + 2 + k];
                            ay += gw * F[4*q + 3 + k];
                            az += gw * F[4*q + 4 + k];
                            aw += gw * F[4*q + 5 + k];
                        }
                        wcb[wcBase + q] = make_float4(ax * rowScale, ay * rowScale,
                                                      az * rowScale, aw * rowScale);
                    }
                }
                __syncthreads();   // A: wcb ready; all W-reads of raw complete
                // ---- H conv: 14 taps shared by the 2-row pair ----
                float4 T[14];
#pragma unroll
                for (int k = 0; k < 14; ++k) T[k] = wcb[tapBase + k * WCS];
#pragma unroll
                for (int k = 0; k < KS; ++k) {
                    const float gw = g[k];
                    whA.x += gw * T[k].x;   whA.y += gw * T[k].y;
                    whA.z += gw * T[k].z;   whA.w += gw * T[k].w;
                    whB.x += gw * T[k+1].x; whB.y += gw * T[k+1].y;
                    whB.z += gw * T[k+1].z; whB.w += gw * T[k+1].w;
                }
            }

            // ---- D window insert + dot ----
            if (off == 0) { WA[12] = whA; WB[12] = whB; }
            else          { WA[13] = whA; WB[13] = whB; }
            if (s2 >= 2 * RAD) {
                const int o = d0 + s - 2 * RAD;        // always < DIM (exact tiling)
                float4 A = z4, B = z4;
#pragma unroll
                for (int j = 0; j < KS; ++j) {
                    const float gw = g[j];
                    const float4 a = WA[j + off];
                    const float4 b = WB[j + off];
                    A.x += gw * a.x; A.y += gw * a.y; A.z += gw * a.z; A.w += gw * a.w;
                    B.x += gw * b.x; B.y += gw * b.y; B.z += gw * b.z; B.w += gw * b.w;
                }
                const int ob = outBase + o * PLANE4;
                __builtin_nontemporal_store(*(const nt4*)&A, (nt4*)&out4[ob]);
                __builtin_nontemporal_store(*(const nt4*)&B, (nt4*)&out4[ob + W4C]);
            }

            // ---- write prefetched plane into raw (W-readers are past barrier A) ----
            if (nv) {
#pragma unroll
                for (int i = 0; i < 5; ++i) raw[dstOff[i]] = pf[i];
            }
            __syncthreads();       // B: raw ready; wcb safe to overwrite next step
        }
        // shift window by 2 (once per pair)
#pragma unroll
        for (int j = 0; j < 12; ++j) { WA[j] = WA[j + 2]; WB[j] = WB[j + 2]; }
    }
}

// Fallback: direct 2197-tap depthwise conv (only if ws_size is too small).
__global__ void naive_conv3d_kernel(const float* __restrict__ x, const float* __restrict__ w,
                                    float* __restrict__ out, int total) {
    int n = blockIdx.x * blockDim.x + threadIdx.x;
    if (n >= total) return;
    int wp = n % DIM;
    int h = (n / DIM) % DIM;
    int d = (n / (DIM * DIM)) % DIM;
    int c = n / (DIM * DIM * DIM);
    const float* wc = w + c * KS * KS * KS;
    const float* xc = x + (size_t)c * DIM * DIM * DIM;
    float acc = 0.f;
    for (int kd = 0; kd < KS; ++kd) {
        int dd = d + kd - RAD;
        if (dd < 0 || dd >= DIM) continue;
        for (int kh = 0; kh < KS; ++kh) {
            int hh = h + kh - RAD;
            if (hh < 0 || hh >= DIM) continue;
            for (int kw = 0; kw < KS; ++kw) {
                int ww = wp + kw - RAD;
                if (ww < 0 || ww >= DIM) continue;
                acc += wc[(kd * KS + kh) * KS + kw] * xc[((size_t)dd * DIM + hh) * DIM + ww];
            }
        }
    }
    out[n] = acc;
}

extern "C" void kernel_launch(void* const* d_in, const int* in_sizes, int n_in,
                              void* d_out, int out_size, void* d_ws, size_t ws_size,
                              hipStream_t stream) {
    const float* x = (const float*)d_in[0];
    const float* w = (const float*)d_in[1];
    float* out = (float*)d_out;

    if (ws_size >= 64) {
        float* g1 = (float*)d_ws;
        g1_extract_kernel<<<1, 64, 0, stream>>>(w, g1);
        conv3d_fused<<<GRIDF, NTF, 0, stream>>>(x, out, g1);
    } else {
        const int threads = 256;
        const int blocks = (TOTAL + threads - 1) / threads;
        naive_conv3d_kernel<<<blocks, threads, 0, stream>>>(x, w, out, TOTAL);
    }
}

// Round 6
// 246.994 us; speedup vs baseline: 1.2696x; 1.2696x over previous
//
#include <hip/hip_runtime.h>

#define RAD 6
#define KS 13
#define DIM 192
#define CH 3
#define W4C 48                  // float4 per row
#define PLANE4 (DIM * W4C)      // f4 per d-plane
#define VOL4 (DIM * PLANE4)     // f4 per channel
#define TOTAL (CH * DIM * DIM * DIM)

// ---------------- fused kernel geometry ----------------
#define WCH 2                   // output f4 cols per block
#define NWT (W4C / WCH)         // 24 w-tiles
#define DT 16                   // output depths per block
#define NDT (DIM / DT)          // 12
#define NSTEP (DT + 2 * RAD)    // 28 planes streamed
#define NTF 384                 // 192 rows x 2 cols
#define GRIDF (CH * NWT * NDT)  // 864 = 8 * 108
#define WROWS (DIM + 2 * RAD)   // 204 wcb storage rows (6 zero-pad each end)

// Extract 1D gaussian: g3[i][j][k] = g1[i]*g1[j]*g1[k], sum(g1)=1 -> row-sum recovers g1.
__global__ void g1_extract_kernel(const float* __restrict__ w, float* __restrict__ g1) {
    int i = threadIdx.x;
    if (i < KS) {
        float s = 0.f;
        for (int j = 0; j < KS * KS; ++j) s += w[i * KS * KS + j];
        g1[i] = s;
    }
}

// ---------------------------------------------------------------------------
// Full-H column block: (c, all 192 h-rows, 2 f4 w-cols, 16 depths).
// Thread (row, cw) owns one output f4 column. Per d-step:
//   issue:  3 global f4 loads (own cols of next plane) -> regs
//   W:      mask + __shfl_xor(1) exchange with row-sibling -> 5-f4 window
//           in regs; 13-tap w-conv -> wcb[s&1] (LDS, h-zero-padded)
//   barrier (single; drains the prefetch loads too)
//   H:      13 LDS taps down the column (pad rows = 0, no branches)
//   D:      14-deep register window, pair-stepped dot; plain store
// wcb double-buffer gives W(s+2)-vs-H(s) two barriers of separation.
// No h-halo W redundancy (58.5 FMA/out vs 104 in the h-tiled slab).
// LDS 13KB; VGPR-capped at 128.
// ---------------------------------------------------------------------------
__global__ __launch_bounds__(NTF, 4) void conv3d_fused(const float* __restrict__ in,
                                                       float* __restrict__ out,
                                                       const float* __restrict__ g1v) {
    __shared__ float4 wcb[2 * WROWS * WCH];

    int bid = blockIdx.x;
    // bijective XCD swizzle: 864 = 8 * 108; adjacent logical wt share an XCD
    bid = (bid & 7) * (GRIDF / 8) + (bid >> 3);
    const int wt = bid % NWT;
    const int dt = (bid / NWT) % NDT;
    const int c  = bid / (NWT * NDT);
    const int d0 = dt * DT;
    const int t  = threadIdx.x;
    const int row = t >> 1;
    const int cw  = t & 1;

    float g[KS];
#pragma unroll
    for (int k = 0; k < KS; ++k) g[k] = g1v[k];

    const float4* __restrict__ in4 = (const float4*)in;
    float4* __restrict__ out4 = (float4*)out;
    const float4 z4 = make_float4(0.f, 0.f, 0.f, 0.f);

    // staged cols: local col = 2*i + cw (even lane: 0,2,4; odd: 1,3,5)
    // global f4 col = wt*2 - 2 + local
    int sOff[3]; float sm[3];
#pragma unroll
    for (int i = 0; i < 3; ++i) {
        int col = wt * WCH - 2 + 2 * i + cw;
        int colc = min(max(col, 0), W4C - 1);
        sOff[i] = c * VOL4 + row * W4C + colc;        // + dp*PLANE4 per step
        sm[i] = (col >= 0 && col < W4C) ? 1.f : 0.f;  // w zero-pad
    }
    const int wcbW = (row + RAD) * WCH + cw;          // write slot
    const int wcbR = row * WCH + cw;                  // read base (+k*WCH)
    const int outB = c * VOL4 + row * W4C + wt * WCH + cw;

    // zero the h-pad rows (rows 0..5 and 198..203) of both buffers
    if (t < 4 * RAD * WCH) {                          // 48 threads
        int b  = t / (2 * RAD * WCH);
        int q  = t % (2 * RAD * WCH);
        int pr = q >> 1;
        int pc = q & 1;
        int r  = (pr < RAD) ? pr : (DIM + pr);        // 0..5 / 198..203
        wcb[b * WROWS * WCH + r * WCH + pc] = z4;
    }

    float4 wd[14];
#pragma unroll
    for (int j = 0; j < 14; ++j) wd[j] = z4;

    float4 pA0 = z4, pA1 = z4, pA2 = z4, pB0 = z4, pB1 = z4, pB2 = z4;
    {   // prologue: plane d0-RAD into the step-0 operand regs
        const int dp0 = d0 - RAD;
        if (dp0 >= 0) {
            const int pb = dp0 * PLANE4;
            pB0 = in4[pb + sOff[0]];
            pB1 = in4[pb + sOff[1]];
            pB2 = in4[pb + sOff[2]];
        }
    }
    __syncthreads();   // pad zeros visible

#define STEP(S, P0, P1, P2, Q0, Q1, Q2, OFF)                                      \
    {                                                                             \
        const int s_ = (S);                                                       \
        const int dp_ = d0 - RAD + s_;                                            \
        const bool dpv_ = (dp_ >= 0) && (dp_ < DIM);   /* block-uniform */        \
        const int dpn_ = dp_ + 1;                                                 \
        const bool nv_ = (s_ + 1 < NSTEP) && (dpn_ >= 0) && (dpn_ < DIM);         \
        if (nv_) {                                     /* prefetch next plane */  \
            const int pb_ = dpn_ * PLANE4;                                        \
            Q0 = in4[pb_ + sOff[0]];                                              \
            Q1 = in4[pb_ + sOff[1]];                                              \
            Q2 = in4[pb_ + sOff[2]];                                              \
        }                                                                         \
        const int bo_ = (s_ & 1) * (WROWS * WCH);                                 \
        if (dpv_) {                                                               \
            float4 m0 = P0, m1 = P1, m2 = P2;                                     \
            m0.x *= sm[0]; m0.y *= sm[0]; m0.z *= sm[0]; m0.w *= sm[0];           \
            m1.x *= sm[1]; m1.y *= sm[1]; m1.z *= sm[1]; m1.w *= sm[1];           \
            m2.x *= sm[2]; m2.y *= sm[2]; m2.z *= sm[2]; m2.w *= sm[2];           \
            float4 t0, t1, t2;                         /* row-sibling exchange */ \
            t0.x = __shfl_xor(m0.x, 1); t0.y = __shfl_xor(m0.y, 1);               \
            t0.z = __shfl_xor(m0.z, 1); t0.w = __shfl_xor(m0.w, 1);               \
            t1.x = __shfl_xor(m1.x, 1); t1.y = __shfl_xor(m1.y, 1);               \
            t1.z = __shfl_xor(m1.z, 1); t1.w = __shfl_xor(m1.w, 1);               \
            t2.x = __shfl_xor(m2.x, 1); t2.y = __shfl_xor(m2.y, 1);               \
            t2.z = __shfl_xor(m2.z, 1); t2.w = __shfl_xor(m2.w, 1);               \
            /* 5-f4 window cols cw..cw+4: [m0, sel, m1, sel, m2] */               \
            const float4 Fb = cw ? t1 : t0;                                       \
            const float4 Fd = cw ? t2 : t1;                                       \
            float F[20];                                                          \
            F[0]=m0.x; F[1]=m0.y; F[2]=m0.z; F[3]=m0.w;                           \
            F[4]=Fb.x; F[5]=Fb.y; F[6]=Fb.z; F[7]=Fb.w;                           \
            F[8]=m1.x; F[9]=m1.y; F[10]=m1.z; F[11]=m1.w;                         \
            F[12]=Fd.x; F[13]=Fd.y; F[14]=Fd.z; F[15]=Fd.w;                       \
            F[16]=m2.x; F[17]=m2.y; F[18]=m2.z; F[19]=m2.w;                       \
            float ax=0.f, ay=0.f, az=0.f, aw=0.f;                                 \
            _Pragma("unroll")                                                     \
            for (int k = 0; k < KS; ++k) {                                        \
                const float gw = g[k];                                            \
                ax += gw * F[k + 2]; ay += gw * F[k + 3];                         \
                az += gw * F[k + 4]; aw += gw * F[k + 5];                         \
            }                                                                     \
            wcb[bo_ + wcbW] = make_float4(ax, ay, az, aw);                        \
        }                                                                         \
        __syncthreads();          /* single barrier: wcb ready + loads drained */ \
        float4 wh = z4;                                                           \
        if (dpv_) {                                                               \
            _Pragma("unroll")                                                     \
            for (int k = 0; k < KS; ++k) {                                        \
                const float4 T = wcb[bo_ + wcbR + k * WCH];                       \
                const float gw = g[k];                                            \
                wh.x += gw * T.x; wh.y += gw * T.y;                               \
                wh.z += gw * T.z; wh.w += gw * T.w;                               \
            }                                                                     \
        }                                                                         \
        wd[12 + (OFF)] = wh;                                                      \
        if (s_ >= 2 * RAD) {                                                      \
            const int o_ = d0 + s_ - 2 * RAD;                                     \
            float4 A = z4;                                                        \
            _Pragma("unroll")                                                     \
            for (int j = 0; j < KS; ++j) {                                        \
                const float gw = g[j];                                            \
                const float4 v = wd[j + (OFF)];                                   \
                A.x += gw * v.x; A.y += gw * v.y;                                 \
                A.z += gw * v.z; A.w += gw * v.w;                                 \
            }                                                                     \
            out4[outB + o_ * PLANE4] = A;                                         \
        }                                                                         \
    }

#pragma unroll 1
    for (int s2 = 0; s2 < NSTEP; s2 += 2) {
        STEP(s2,     pB0, pB1, pB2, pA0, pA1, pA2, 0)
        STEP(s2 + 1, pA0, pA1, pA2, pB0, pB1, pB2, 1)
#pragma unroll
        for (int j = 0; j < 12; ++j) wd[j] = wd[j + 2];   // pair shift
    }
#undef STEP
}

// Fallback: direct 2197-tap depthwise conv (only if ws_size is too small).
__global__ void naive_conv3d_kernel(const float* __restrict__ x, const float* __restrict__ w,
                                    float* __restrict__ out, int total) {
    int n = blockIdx.x * blockDim.x + threadIdx.x;
    if (n >= total) return;
    int wp = n % DIM;
    int h = (n / DIM) % DIM;
    int d = (n / (DIM * DIM)) % DIM;
    int c = n / (DIM * DIM * DIM);
    const float* wc = w + c * KS * KS * KS;
    const float* xc = x + (size_t)c * DIM * DIM * DIM;
    float acc = 0.f;
    for (int kd = 0; kd < KS; ++kd) {
        int dd = d + kd - RAD;
        if (dd < 0 || dd >= DIM) continue;
        for (int kh = 0; kh < KS; ++kh) {
            int hh = h + kh - RAD;
            if (hh < 0 || hh >= DIM) continue;
            for (int kw = 0; kw < KS; ++kw) {
                int ww = wp + kw - RAD;
                if (ww < 0 || ww >= DIM) continue;
                acc += wc[(kd * KS + kh) * KS + kw] * xc[((size_t)dd * DIM + hh) * DIM + ww];
            }
        }
    }
    out[n] = acc;
}

extern "C" void kernel_launch(void* const* d_in, const int* in_sizes, int n_in,
                              void* d_out, int out_size, void* d_ws, size_t ws_size,
                              hipStream_t stream) {
    const float* x = (const float*)d_in[0];
    const float* w = (const float*)d_in[1];
    float* out = (float*)d_out;

    if (ws_size >= 64) {
        float* g1 = (float*)d_ws;
        g1_extract_kernel<<<1, 64, 0, stream>>>(w, g1);
        conv3d_fused<<<GRIDF, NTF, 0, stream>>>(x, out, g1);
    } else {
        const int threads = 256;
        const int blocks = (TOTAL + threads - 1) / threads;
        naive_conv3d_kernel<<<blocks, threads, 0, stream>>>(x, w, out, TOTAL);
    }
}

// Round 8
// 246.286 us; speedup vs baseline: 1.2733x; 1.0029x over previous
//
#include <hip/hip_runtime.h>

#define RAD 6
#define KS 13
#define DIM 192
#define CH 3
#define W4C 48                  // float4 per row
#define PLANE4 (DIM * W4C)      // f4 per d-plane
#define VOL4 (DIM * PLANE4)     // f4 per channel
#define TOTAL (CH * DIM * DIM * DIM)

// ---------------- fused kernel geometry ----------------
#define WCH 2                   // output f4 cols per block
#define NWT (W4C / WCH)         // 24 w-tiles
#define DT 16                   // output depths per block
#define NDT (DIM / DT)          // 12
#define NSTEP (DT + 2 * RAD)    // 28 planes streamed
#define NTF 384                 // 192 rows x 2 cols
#define GRIDF (CH * NWT * NDT)  // 864 = 8 * 108
#define WROWS (DIM + 2 * RAD)   // 204 wcb storage rows (6 zero-pad each end)

// Extract 1D gaussian: g3[i][j][k] = g1[i]*g1[j]*g1[k], sum(g1)=1 -> row-sum recovers g1.
__global__ void g1_extract_kernel(const float* __restrict__ w, float* __restrict__ g1) {
    int i = threadIdx.x;
    if (i < KS) {
        float s = 0.f;
        for (int j = 0; j < KS * KS; ++j) s += w[i * KS * KS + j];
        g1[i] = s;
    }
}

// ---------------------------------------------------------------------------
// Full-H column block: (c, all 192 h-rows, 2 f4 w-cols, 16 depths).
// Thread (row, cw) owns one output f4 column. Per d-step:
//   issue:  3 global f4 loads (own cols of next plane) -> regs (stay in
//           flight ACROSS the barrier; waited only at next step's W use)
//   W:      mask + __shfl_xor(1) exchange with row-sibling -> 5-f4 window
//           in regs; 13-tap w-conv -> wcb[s&1] (LDS, h-zero-padded)
//   barrier: s_waitcnt lgkmcnt(0) + raw s_barrier (NO vmcnt drain -- this
//           is the T4 fix; __syncthreads would drain the prefetch loads)
//   H:      13 LDS taps down the column (pad rows = 0, no branches)
//   D:      14-deep register window, pair-stepped dot; plain store
// wcb double-buffer gives W(s+2)-vs-H(s) two barriers of separation.
// ---------------------------------------------------------------------------
__global__ __launch_bounds__(NTF, 4) void conv3d_fused(const float* __restrict__ in,
                                                       float* __restrict__ out,
                                                       const float* __restrict__ g1v) {
    __shared__ float4 wcb[2 * WROWS * WCH];

    int bid = blockIdx.x;
    // bijective XCD swizzle: 864 = 8 * 108; adjacent logical wt share an XCD
    bid = (bid & 7) * (GRIDF / 8) + (bid >> 3);
    const int wt = bid % NWT;
    const int dt = (bid / NWT) % NDT;
    const int c  = bid / (NWT * NDT);
    const int d0 = dt * DT;
    const int t  = threadIdx.x;
    const int row = t >> 1;
    const int cw  = t & 1;

    float g[KS];
#pragma unroll
    for (int k = 0; k < KS; ++k) g[k] = g1v[k];

    const float4* __restrict__ in4 = (const float4*)in;
    float4* __restrict__ out4 = (float4*)out;
    const float4 z4 = make_float4(0.f, 0.f, 0.f, 0.f);

    // staged cols: local col = 2*i + cw (even lane: 0,2,4; odd: 1,3,5)
    // global f4 col = wt*2 - 2 + local
    int sOff[3]; float sm[3];
#pragma unroll
    for (int i = 0; i < 3; ++i) {
        int col = wt * WCH - 2 + 2 * i + cw;
        int colc = min(max(col, 0), W4C - 1);
        sOff[i] = c * VOL4 + row * W4C + colc;        // + dp*PLANE4 per step
        sm[i] = (col >= 0 && col < W4C) ? 1.f : 0.f;  // w zero-pad
    }
    const int wcbW = (row + RAD) * WCH + cw;          // write slot
    const int wcbR = row * WCH + cw;                  // read base (+k*WCH)
    const int outB = c * VOL4 + row * W4C + wt * WCH + cw;

    // zero the h-pad rows (rows 0..5 and 198..203) of both buffers
    if (t < 4 * RAD * WCH) {                          // 48 threads
        int b  = t / (2 * RAD * WCH);
        int q  = t % (2 * RAD * WCH);
        int pr = q >> 1;
        int pc = q & 1;
        int r  = (pr < RAD) ? pr : (DIM + pr);        // 0..5 / 198..203
        wcb[b * WROWS * WCH + r * WCH + pc] = z4;
    }

    float4 wd[14];
#pragma unroll
    for (int j = 0; j < 14; ++j) wd[j] = z4;

    float4 pA0 = z4, pA1 = z4, pA2 = z4, pB0 = z4, pB1 = z4, pB2 = z4;
    {   // prologue: plane d0-RAD into the step-0 operand regs
        const int dp0 = d0 - RAD;
        if (dp0 >= 0) {
            const int pb = dp0 * PLANE4;
            pB0 = in4[pb + sOff[0]];
            pB1 = in4[pb + sOff[1]];
            pB2 = in4[pb + sOff[2]];
        }
    }
    __syncthreads();   // pad zeros visible (once; full drain is fine here)

#define STEP(S, P0, P1, P2, Q0, Q1, Q2, OFF)                                      \
    {                                                                             \
        const int s_ = (S);                                                       \
        const int dp_ = d0 - RAD + s_;                                            \
        const bool dpv_ = (dp_ >= 0) && (dp_ < DIM);   /* block-uniform */        \
        const int dpn_ = dp_ + 1;                                                 \
        const bool nv_ = (s_ + 1 < NSTEP) && (dpn_ >= 0) && (dpn_ < DIM);         \
        if (nv_) {                                     /* prefetch next plane */  \
            const int pb_ = dpn_ * PLANE4;                                        \
            Q0 = in4[pb_ + sOff[0]];                                              \
            Q1 = in4[pb_ + sOff[1]];                                              \
            Q2 = in4[pb_ + sOff[2]];                                              \
        }                                                                         \
        const int bo_ = (s_ & 1) * (WROWS * WCH);                                 \
        if (dpv_) {                                                               \
            float4 m0 = P0, m1 = P1, m2 = P2;                                     \
            m0.x *= sm[0]; m0.y *= sm[0]; m0.z *= sm[0]; m0.w *= sm[0];           \
            m1.x *= sm[1]; m1.y *= sm[1]; m1.z *= sm[1]; m1.w *= sm[1];           \
            m2.x *= sm[2]; m2.y *= sm[2]; m2.z *= sm[2]; m2.w *= sm[2];           \
            float4 t0, t1, t2;                         /* row-sibling exchange */ \
            t0.x = __shfl_xor(m0.x, 1); t0.y = __shfl_xor(m0.y, 1);               \
            t0.z = __shfl_xor(m0.z, 1); t0.w = __shfl_xor(m0.w, 1);               \
            t1.x = __shfl_xor(m1.x, 1); t1.y = __shfl_xor(m1.y, 1);               \
            t1.z = __shfl_xor(m1.z, 1); t1.w = __shfl_xor(m1.w, 1);               \
            t2.x = __shfl_xor(m2.x, 1); t2.y = __shfl_xor(m2.y, 1);               \
            t2.z = __shfl_xor(m2.z, 1); t2.w = __shfl_xor(m2.w, 1);               \
            /* 5-f4 window cols cw..cw+4: [m0, sel, m1, sel, m2] */               \
            const float4 Fb = cw ? t1 : t0;                                       \
            const float4 Fd = cw ? t2 : t1;                                       \
            float F[20];                                                          \
            F[0]=m0.x; F[1]=m0.y; F[2]=m0.z; F[3]=m0.w;                           \
            F[4]=Fb.x; F[5]=Fb.y; F[6]=Fb.z; F[7]=Fb.w;                           \
            F[8]=m1.x; F[9]=m1.y; F[10]=m1.z; F[11]=m1.w;                         \
            F[12]=Fd.x; F[13]=Fd.y; F[14]=Fd.z; F[15]=Fd.w;                       \
            F[16]=m2.x; F[17]=m2.y; F[18]=m2.z; F[19]=m2.w;                       \
            float ax=0.f, ay=0.f, az=0.f, aw=0.f;                                 \
            _Pragma("unroll")                                                     \
            for (int k = 0; k < KS; ++k) {                                        \
                const float gw = g[k];                                            \
                ax += gw * F[k + 2]; ay += gw * F[k + 3];                         \
                az += gw * F[k + 4]; aw += gw * F[k + 5];                         \
            }                                                                     \
            wcb[bo_ + wcbW] = make_float4(ax, ay, az, aw);                        \
        }                                                                         \
        /* T4 barrier: LDS visibility only; global prefetch stays in flight */    \
        asm volatile("s_waitcnt lgkmcnt(0)" ::: "memory");                        \
        __builtin_amdgcn_s_barrier();                                             \
        asm volatile("" ::: "memory");                                            \
        float4 wh = z4;                                                           \
        if (dpv_) {                                                               \
            _Pragma("unroll")                                                     \
            for (int k = 0; k < KS; ++k) {                                        \
                const float4 T = wcb[bo_ + wcbR + k * WCH];                       \
                const float gw = g[k];                                            \
                wh.x += gw * T.x; wh.y += gw * T.y;                               \
                wh.z += gw * T.z; wh.w += gw * T.w;                               \
            }                                                                     \
        }                                                                         \
        wd[12 + (OFF)] = wh;                                                      \
        if (s_ >= 2 * RAD) {                                                      \
            const int o_ = d0 + s_ - 2 * RAD;                                     \
            float4 A = z4;                                                        \
            _Pragma("unroll")                                                     \
            for (int j = 0; j < KS; ++j) {                                        \
                const float gw = g[j];                                            \
                const float4 v = wd[j + (OFF)];                                   \
                A.x += gw * v.x; A.y += gw * v.y;                                 \
                A.z += gw * v.z; A.w += gw * v.w;                                 \
            }                                                                     \
            out4[outB + o_ * PLANE4] = A;                                         \
        }                                                                         \
    }

#pragma unroll 1
    for (int s2 = 0; s2 < NSTEP; s2 += 2) {
        STEP(s2,     pB0, pB1, pB2, pA0, pA1, pA2, 0)
        STEP(s2 + 1, pA0, pA1, pA2, pB0, pB1, pB2, 1)
#pragma unroll
        for (int j = 0; j < 12; ++j) wd[j] = wd[j + 2];   // pair shift
    }
#undef STEP
}

// Fallback: direct 2197-tap depthwise conv (only if ws_size is too small).
__global__ void naive_conv3d_kernel(const float* __restrict__ x, const float* __restrict__ w,
                                    float* __restrict__ out, int total) {
    int n = blockIdx.x * blockDim.x + threadIdx.x;
    if (n >= total) return;
    int wp = n % DIM;
    int h = (n / DIM) % DIM;
    int d = (n / (DIM * DIM)) % DIM;
    int c = n / (DIM * DIM * DIM);
    const float* wc = w + c * KS * KS * KS;
    const float* xc = x + (size_t)c * DIM * DIM * DIM;
    float acc = 0.f;
    for (int kd = 0; kd < KS; ++kd) {
        int dd = d + kd - RAD;
        if (dd < 0 || dd >= DIM) continue;
        for (int kh = 0; kh < KS; ++kh) {
            int hh = h + kh - RAD;
            if (hh < 0 || hh >= DIM) continue;
            for (int kw = 0; kw < KS; ++kw) {
                int ww = wp + kw - RAD;
                if (ww < 0 || ww >= DIM) continue;
                acc += wc[(kd * KS + kh) * KS + kw] * xc[((size_t)dd * DIM + hh) * DIM + ww];
            }
        }
    }
    out[n] = acc;
}

extern "C" void kernel_launch(void* const* d_in, const int* in_sizes, int n_in,
                              void* d_out, int out_size, void* d_ws, size_t ws_size,
                              hipStream_t stream) {
    const float* x = (const float*)d_in[0];
    const float* w = (const float*)d_in[1];
    float* out = (float*)d_out;

    if (ws_size >= 64) {
        float* g1 = (float*)d_ws;
        g1_extract_kernel<<<1, 64, 0, stream>>>(w, g1);
        conv3d_fused<<<GRIDF, NTF, 0, stream>>>(x, out, g1);
    } else {
        const int threads = 256;
        const int blocks = (TOTAL + threads - 1) / threads;
        naive_conv3d_kernel<<<blocks, threads, 0, stream>>>(x, w, out, TOTAL);
    }
}